// Round 12
// baseline (307.781 us; speedup 1.0000x reference)
//
#include <hip/hip_runtime.h>
#include <hip/hip_bf16.h>

#define B_ 32
#define T_ 512
#define TP_ 514          /* padded rows per batch */
#define L_ 2048
#define H_ 512
#define NRR (B_*T_)      /* 16384 rows */
#define KC_ 1536         /* 3*H */
#define NB_ 256
#define EPS_ 1e-5f
#define XPE ((size_t)B_ * TP_ * H_)   /* elems per padded buffer */

typedef __bf16 bf16;
typedef __bf16 bf16x8 __attribute__((ext_vector_type(8)));
typedef float f32x4 __attribute__((ext_vector_type(4)));

static const size_t WC_BYTES  = (size_t)6 * H_ * KC_ * 2;       // 9,437,184
static const size_t XP_BYTES  = XPE * 2;                        // 16,842,752
static const size_t Y_BYTES   = (size_t)3 * NRR * H_ * 2;       // 50,331,648

__device__ __forceinline__ void gload16(const void* g, void* l) {
    __builtin_amdgcn_global_load_lds(
        (const __attribute__((address_space(1))) unsigned int*)g,
        (__attribute__((address_space(3))) unsigned int*)l, 16, 0, 0);
}

// ---------------- weight repack: w[i][o][c][k] -> Wc[m][o][k*H + c] (bf16) ----
__global__ void k_prep_wc(const float* __restrict__ wd, const float* __restrict__ wp,
                          const float* __restrict__ we, bf16* __restrict__ wc) {
    int e = blockIdx.x * 256 + threadIdx.x;
    if (e >= 6 * H_ * KC_) return;
    int m   = e / (H_ * KC_);
    int rem = e % (H_ * KC_);
    int o  = rem / KC_;
    int r2 = rem % KC_;
    int k  = r2 / H_;
    int c  = r2 % H_;
    int p = m >> 1, i = m & 1;
    const float* w = (p == 0) ? wd : (p == 1 ? wp : we);
    float v = w[((size_t)i * H_ * H_ + (size_t)o * H_ + c) * 3 + k];
    wc[e] = (bf16)v;
}

// ---------------- padded bf16 input + zero pad rows of the 3 xp1 buffers -----
__global__ void k_pad(const float* __restrict__ x, bf16* __restrict__ xp0,
                      bf16* __restrict__ xp1) {
    int wid = threadIdx.x >> 6, lane = threadIdx.x & 63;
    int row = blockIdx.x * 4 + wid;               // 0 .. 32*514-1
    int b = row / TP_, tp = row % TP_;
    bf16* d0 = xp0 + (size_t)row * H_ + lane * 8;
    if (tp == 0 || tp == TP_ - 1) {
        bf16x8 z;
#pragma unroll
        for (int i = 0; i < 8; ++i) z[i] = (bf16)0.0f;
        *(bf16x8*)d0 = z;
#pragma unroll
        for (int p = 0; p < 3; ++p)
            *(bf16x8*)(xp1 + p * XPE + (size_t)row * H_ + lane * 8) = z;
    } else {
        const f32x4* p = (const f32x4*)(x + ((size_t)(b * T_ + tp - 1)) * H_ + lane * 8);
        f32x4 u = p[0], v = p[1];
        bf16x8 o;
        o[0] = (bf16)u[0]; o[1] = (bf16)u[1]; o[2] = (bf16)u[2]; o[3] = (bf16)u[3];
        o[4] = (bf16)v[0]; o[5] = (bf16)v[1]; o[6] = (bf16)v[2]; o[7] = (bf16)v[3];
        *(bf16x8*)d0 = o;
    }
}

// ---------------- per-batch inclusive scan of durations ----------------------
__global__ void k_scan(const int* __restrict__ dur, int* __restrict__ csum,
                       float* __restrict__ mel_out) {
    int b = blockIdx.x, t = threadIdx.x;
    __shared__ int s[T_];
    s[t] = dur[b * T_ + t];
    __syncthreads();
    for (int off = 1; off < T_; off <<= 1) {
        int v = (t >= off) ? s[t - off] : 0;
        __syncthreads();
        s[t] += v;
        __syncthreads();
    }
    csum[b * T_ + t] = s[t];
    if (t == T_ - 1) mel_out[b] = (float)((s[t] < L_) ? s[t] : L_);
}

// -------- length regulate + inline bucketize + (x + p_emb + e_emb) gather ----
__global__ void k_gather(const float* __restrict__ x, const float* __restrict__ pemb,
                         const float* __restrict__ eemb, const float* __restrict__ pt,
                         const float* __restrict__ et, const float* __restrict__ pbins,
                         const float* __restrict__ ebins, const int* __restrict__ csum,
                         float* __restrict__ out) {
    int bi = blockIdx.x;
    int b  = bi >> 5;
    int lbase = (bi & 31) * 64;
    __shared__ int cs[T_];
    __shared__ float pb[NB_ - 1], eb[NB_ - 1];
    cs[threadIdx.x]       = csum[b * T_ + threadIdx.x];
    cs[threadIdx.x + 256] = csum[b * T_ + threadIdx.x + 256];
    if (threadIdx.x < NB_ - 1) {
        pb[threadIdx.x] = pbins[threadIdx.x];
        eb[threadIdx.x] = ebins[threadIdx.x];
    }
    __syncthreads();
    int wid = threadIdx.x >> 6, lane = threadIdx.x & 63;
    int mel = cs[T_ - 1]; if (mel > L_) mel = L_;
#pragma unroll 1
    for (int it = 0; it < 16; ++it) {
        int l = lbase + it * 4 + wid;
        float* op = out + ((size_t)(b * L_ + l)) * H_ + lane * 8;
        if (l >= mel) {
            f32x4 z = {0.f, 0.f, 0.f, 0.f};
            ((f32x4*)op)[0] = z;
            ((f32x4*)op)[1] = z;
            continue;
        }
        int lo = 0, hi = T_;
        while (lo < hi) { int mid = (lo + hi) >> 1; if (cs[mid] <= l) lo = mid + 1; else hi = mid; }
        int idx = (lo < T_ - 1) ? lo : (T_ - 1);
        int rr = b * T_ + idx;
        float pv = pt[rr], ev = et[rr];
        int pi, ei;
        { int a = 0, c = NB_ - 1; while (a < c) { int mid = (a + c) >> 1; if (pb[mid] < pv) a = mid + 1; else c = mid; } pi = a; }
        { int a = 0, c = NB_ - 1; while (a < c) { int mid = (a + c) >> 1; if (eb[mid] < ev) a = mid + 1; else c = mid; } ei = a; }
        const f32x4* xp = (const f32x4*)(x    + (size_t)rr * H_ + lane * 8);
        const f32x4* pp = (const f32x4*)(pemb + (size_t)pi * H_ + lane * 8);
        const f32x4* ep = (const f32x4*)(eemb + (size_t)ei * H_ + lane * 8);
        ((f32x4*)op)[0] = xp[0] + pp[0] + ep[0];
        ((f32x4*)op)[1] = xp[1] + pp[1] + ep[1];
    }
}

// ============ conv-aware GEMM, tall waves: BM=256 BN=128 H-chunk=32 ==========
// 4 waves (2M x 2N), per-wave 128x64 out (acc[8][4]) -> operand-bytes/FLOP cut
// 25% vs 64x64. A staged once per chunk as 272-row slab (tap-reuse); 16 steps.
// Rows are 64B (4 chunks): swizzle key = (row>>1)&3 both sides (balanced ->
// 2-way, free). Staging: 16 rows/gload16, lane: row=lane>>2, chunk=lane&3,
// key=(lane>>3)&3. T1: 768 = 8 XCD x (12 colblk x 8 rowblk), colblk-major.
template<int LAYER>
__global__ __launch_bounds__(256)
void k_gemm(const bf16* __restrict__ Xp, const bf16* __restrict__ Wall,
            const float* __restrict__ cb0, const float* __restrict__ cb1,
            const float* __restrict__ cb2, bf16* __restrict__ Y) {
    __shared__ bf16 lA[272 * 32];        // 17,408 B
    __shared__ bf16 lB[384 * 32];        // 24,576 B

    int bid = blockIdx.x;
    int xcd = bid & 7, idx = bid >> 3;   // 768 blocks: idx 0..95
    int colblk = idx >> 3;               // 0..11 (colblk-major per XCD)
    int rowblk = xcd * 8 + (idx & 7);    // 0..63
    int p  = colblk >> 2;
    int oB = (colblk & 3) * 128;
    int rowBase = rowblk * 256;

    const bf16* A = (LAYER == 0) ? Xp : (Xp + (size_t)p * XPE);
    const bf16* W = Wall + ((size_t)(2 * p + LAYER) * H_ + oB) * KC_;
    const float* cbp  = (p == 0) ? cb0 : (p == 1 ? cb1 : cb2);
    const float* bias = cbp + LAYER * H_;

    int tid = threadIdx.x;
    int wid = tid >> 6, lane = tid & 63;
    int wm = wid >> 1, wn = wid & 1;     // 2M x 2N waves, per-wave 128x64
    int lr = lane & 15, kq = lane >> 4;
    int srow = lane >> 2;                // staging: row-in-16
    int csw  = (((lane & 3) ^ ((lane >> 3) & 3)) << 3);   // src col, elems
    int b = rowBase >> 9, t0 = rowBase & (T_ - 1);
    const bf16* Abase = A + ((size_t)(b * TP_ + t0)) * H_;

    f32x4 acc[8][4];
#pragma unroll
    for (int m = 0; m < 8; ++m)
#pragma unroll
        for (int n = 0; n < 4; ++n) acc[m][n] = (f32x4){0.f, 0.f, 0.f, 0.f};

    for (int s = 0; s < 16; ++s) {
        int c0 = s * 32;
        // ---- stage A: 17 gloads x 16 rows (272 rows; rows>257 unread) ----
#pragma unroll
        for (int q = 0; q < 5; ++q) {
            int g = q * 4 + wid;
            if (g < 17)
                gload16(Abase + (size_t)(g * 16 + srow) * H_ + c0 + csw, &lA[g * 16 * 32]);
        }
        // ---- stage B: 24 gloads x 16 rows (3 taps x 128 cols) ----
#pragma unroll
        for (int q = 0; q < 6; ++q) {
            int g = q * 4 + wid;
            int tap = g >> 3;
            int o = ((g & 7) * 16) + srow;
            gload16(W + (size_t)o * KC_ + tap * H_ + c0 + csw, &lB[g * 16 * 32]);
        }
        __syncthreads();   // compiler drains vmcnt before barrier

#pragma unroll
        for (int tap = 0; tap < 3; ++tap) {
            bf16x8 af[8], bfr[4];
#pragma unroll
            for (int n = 0; n < 4; ++n) {
                int row = tap * 128 + wn * 64 + n * 16 + lr;
                bfr[n] = *(const bf16x8*)&lB[row * 32 + ((kq ^ ((row >> 1) & 3)) << 3)];
            }
#pragma unroll
            for (int m = 0; m < 8; ++m) {
                int row = wm * 128 + m * 16 + lr + tap;
                af[m] = *(const bf16x8*)&lA[row * 32 + ((kq ^ ((row >> 1) & 3)) << 3)];
            }
#pragma unroll
            for (int m = 0; m < 8; ++m)
#pragma unroll
                for (int n = 0; n < 4; ++n)
                    acc[m][n] = __builtin_amdgcn_mfma_f32_16x16x32_bf16(
                        af[m], bfr[n], acc[m][n], 0, 0, 0);
        }
        __syncthreads();
    }

    // D layout: col = lane&15 (o), row = 4*(lane>>4) + reg
#pragma unroll
    for (int n = 0; n < 4; ++n) {
        int o = oB + wn * 64 + n * 16 + lr;
        float bi = bias[o];
#pragma unroll
        for (int m = 0; m < 8; ++m) {
            int row = rowBase + wm * 128 + m * 16 + 4 * kq;
#pragma unroll
            for (int r = 0; r < 4; ++r)
                Y[((size_t)p * NRR + row + r) * H_ + o] = (bf16)fmaxf(acc[m][n][r] + bi, 0.f);
        }
    }
}

// ---------------- batched LayerNorm (layer-0) -> padded xp1[p] ---------------
__global__ void k_ln_store(const bf16* __restrict__ Yin,
                           const float* __restrict__ g0, const float* __restrict__ g1,
                           const float* __restrict__ g2,
                           const float* __restrict__ bb0, const float* __restrict__ bb1,
                           const float* __restrict__ bb2, bf16* __restrict__ xp1) {
    int wid = threadIdx.x >> 6, lane = threadIdx.x & 63;
    int rg = blockIdx.x * 4 + wid;
    int p = rg >> 14, r = rg & (NRR - 1);
    const float* g   = (p == 0) ? g0 : (p == 1 ? g1 : g2);
    const float* bta = (p == 0) ? bb0 : (p == 1 ? bb1 : bb2);
    bf16x8 a = *(const bf16x8*)(Yin + ((size_t)p * NRR + r) * H_ + lane * 8);
    float f[8];
#pragma unroll
    for (int i = 0; i < 8; ++i) f[i] = (float)a[i];
    float s1 = 0.f, s2 = 0.f;
#pragma unroll
    for (int i = 0; i < 8; ++i) { s1 += f[i]; s2 += f[i] * f[i]; }
    for (int m = 1; m < 64; m <<= 1) { s1 += __shfl_xor(s1, m); s2 += __shfl_xor(s2, m); }
    float mean = s1 * (1.f / H_);
    float var  = s2 * (1.f / H_) - mean * mean;
    float rs   = rsqrtf(var + EPS_);
    const f32x4* gp = (const f32x4*)g;
    const f32x4* bp = (const f32x4*)bta;
    f32x4 ga = gp[lane * 2], gb = gp[lane * 2 + 1];
    f32x4 ba = bp[lane * 2], bbv = bp[lane * 2 + 1];
    bf16x8 o;
    o[0] = (bf16)((f[0] - mean) * rs * ga[0] + ba[0]);
    o[1] = (bf16)((f[1] - mean) * rs * ga[1] + ba[1]);
    o[2] = (bf16)((f[2] - mean) * rs * ga[2] + ba[2]);
    o[3] = (bf16)((f[3] - mean) * rs * ga[3] + ba[3]);
    o[4] = (bf16)((f[4] - mean) * rs * gb[0] + bbv[0]);
    o[5] = (bf16)((f[5] - mean) * rs * gb[1] + bbv[1]);
    o[6] = (bf16)((f[6] - mean) * rs * gb[2] + bbv[2]);
    o[7] = (bf16)((f[7] - mean) * rs * gb[3] + bbv[3]);
    int bb = r >> 9, t = r & (T_ - 1);
    *(bf16x8*)(xp1 + (size_t)p * XPE + ((size_t)(bb * TP_ + t + 1)) * H_ + lane * 8) = o;
}

// ---------------- batched LayerNorm (layer-1) + linear H->1 + mask -----------
__global__ void k_ln_linear(const bf16* __restrict__ Yin,
                            const float* __restrict__ g0, const float* __restrict__ g1,
                            const float* __restrict__ g2,
                            const float* __restrict__ bb0, const float* __restrict__ bb1,
                            const float* __restrict__ bb2,
                            const float* __restrict__ w0p, const float* __restrict__ w1p,
                            const float* __restrict__ w2p,
                            const float* __restrict__ lb0, const float* __restrict__ lb1,
                            const float* __restrict__ lb2,
                            const unsigned char* __restrict__ mask,
                            float* __restrict__ o0, float* __restrict__ o1,
                            float* __restrict__ o2) {
    int wid = threadIdx.x >> 6, lane = threadIdx.x & 63;
    int rg = blockIdx.x * 4 + wid;
    int p = rg >> 14, r = rg & (NRR - 1);
    const float* g   = ((p == 0) ? g0 : (p == 1 ? g1 : g2)) + H_;
    const float* bta = ((p == 0) ? bb0 : (p == 1 ? bb1 : bb2)) + H_;
    const float* lw  = (p == 0) ? w0p : (p == 1 ? w1p : w2p);
    const float* lb  = (p == 0) ? lb0 : (p == 1 ? lb1 : lb2);
    float*       op  = (p == 0) ? o0 : (p == 1 ? o1 : o2);
    bf16x8 a = *(const bf16x8*)(Yin + ((size_t)p * NRR + r) * H_ + lane * 8);
    float f[8];
#pragma unroll
    for (int i = 0; i < 8; ++i) f[i] = (float)a[i];
    float s1 = 0.f, s2 = 0.f;
#pragma unroll
    for (int i = 0; i < 8; ++i) { s1 += f[i]; s2 += f[i] * f[i]; }
    for (int m = 1; m < 64; m <<= 1) { s1 += __shfl_xor(s1, m); s2 += __shfl_xor(s2, m); }
    float mean = s1 * (1.f / H_);
    float var  = s2 * (1.f / H_) - mean * mean;
    float rs   = rsqrtf(var + EPS_);
    const f32x4* gp = (const f32x4*)g;
    const f32x4* bp = (const f32x4*)bta;
    const f32x4* wp = (const f32x4*)lw;
    f32x4 ga = gp[lane * 2], gb = gp[lane * 2 + 1];
    f32x4 ba = bp[lane * 2], bbv = bp[lane * 2 + 1];
    f32x4 wa = wp[lane * 2], wb = wp[lane * 2 + 1];
    float s = ((f[0] - mean) * rs * ga[0] + ba[0]) * wa[0]
            + ((f[1] - mean) * rs * ga[1] + ba[1]) * wa[1]
            + ((f[2] - mean) * rs * ga[2] + ba[2]) * wa[2]
            + ((f[3] - mean) * rs * ga[3] + ba[3]) * wa[3]
            + ((f[4] - mean) * rs * gb[0] + bbv[0]) * wb[0]
            + ((f[5] - mean) * rs * gb[1] + bbv[1]) * wb[1]
            + ((f[6] - mean) * rs * gb[2] + bbv[2]) * wb[2]
            + ((f[7] - mean) * rs * gb[3] + bbv[3]) * wb[3];
    for (int m = 1; m < 64; m <<= 1) s += __shfl_xor(s, m);
    if (lane == 0) op[r] = mask[r] ? 0.f : (s + lb[0]);
}

extern "C" void kernel_launch(void* const* d_in, const int* in_sizes, int n_in,
                              void* d_out, int out_size, void* d_ws, size_t ws_size,
                              hipStream_t stream) {
    const float* x  = (const float*)d_in[0];
    const unsigned char* mask = (const unsigned char*)d_in[1];
    const int*   dur = (const int*)d_in[2];
    const float* pt  = (const float*)d_in[3];
    const float* et  = (const float*)d_in[4];
    const float* cw[3]    = {(const float*)d_in[6],  (const float*)d_in[12], (const float*)d_in[18]};
    const float* cb[3]    = {(const float*)d_in[7],  (const float*)d_in[13], (const float*)d_in[19]};
    const float* lg[3]    = {(const float*)d_in[8],  (const float*)d_in[14], (const float*)d_in[20]};
    const float* lbn[3]   = {(const float*)d_in[9],  (const float*)d_in[15], (const float*)d_in[21]};
    const float* lw[3]    = {(const float*)d_in[10], (const float*)d_in[16], (const float*)d_in[22]};
    const float* lbias[3] = {(const float*)d_in[11], (const float*)d_in[17], (const float*)d_in[23]};
    const float* pbins = (const float*)d_in[24];
    const float* ebins = (const float*)d_in[25];
    const float* pemb  = (const float*)d_in[26];
    const float* eemb  = (const float*)d_in[27];

    float* out0 = (float*)d_out;
    const size_t OUT0 = (size_t)B_ * L_ * H_;
    float* pitch_out  = out0 + OUT0;
    float* energy_out = pitch_out + NRR;
    float* logd_out   = energy_out + NRR;
    float* mel_out    = logd_out + NRR;

    char* ws = (char*)d_ws;
    bf16*  wc   = (bf16*)ws;
    bf16*  xp0  = (bf16*)(ws + WC_BYTES);
    bf16*  xp1  = (bf16*)(ws + WC_BYTES + XP_BYTES);          // 3 buffers
    bf16*  y    = (bf16*)(ws + WC_BYTES + 4 * XP_BYTES);      // [3][NRR][512]
    int*   csum = (int*)(ws + WC_BYTES + 4 * XP_BYTES + Y_BYTES);

    k_prep_wc<<<(6 * H_ * KC_ + 255) / 256, 256, 0, stream>>>(cw[0], cw[1], cw[2], wc);
    k_pad<<<B_ * TP_ / 4, 256, 0, stream>>>(x, xp0, xp1);
    k_scan<<<B_, T_, 0, stream>>>(dur, csum, mel_out);
    k_gather<<<B_ * 32, 256, 0, stream>>>(x, pemb, eemb, pt, et, pbins, ebins, csum, out0);

    k_gemm<0><<<768, 256, 0, stream>>>(xp0, wc, cb[0], cb[1], cb[2], y);
    k_ln_store<<<3 * NRR / 4, 256, 0, stream>>>(y, lg[0], lg[1], lg[2],
                                                lbn[0], lbn[1], lbn[2], xp1);
    k_gemm<1><<<768, 256, 0, stream>>>(xp1, wc, cb[0], cb[1], cb[2], y);
    k_ln_linear<<<3 * NRR / 4, 256, 0, stream>>>(y, lg[0], lg[1], lg[2],
                                                 lbn[0], lbn[1], lbn[2],
                                                 lw[0], lw[1], lw[2],
                                                 lbias[0], lbias[1], lbias[2],
                                                 mask, logd_out, pitch_out, energy_out);
}

// Round 13
// 244.969 us; speedup vs baseline: 1.2564x; 1.2564x over previous
//
#include <hip/hip_runtime.h>
#include <hip/hip_bf16.h>

#define B_ 32
#define T_ 512
#define TP_ 514          /* padded rows per batch */
#define L_ 2048
#define H_ 512
#define NRR (B_*T_)      /* 16384 rows */
#define KC_ 1536         /* 3*H */
#define NB_ 256
#define EPS_ 1e-5f
#define XPE ((size_t)B_ * TP_ * H_)   /* elems per padded buffer */

typedef __bf16 bf16;
typedef __bf16 bf16x8 __attribute__((ext_vector_type(8)));
typedef float f32x4 __attribute__((ext_vector_type(4)));

static const size_t WC_BYTES  = (size_t)6 * H_ * KC_ * 2;       // 9,437,184
static const size_t XP_BYTES  = XPE * 2;                        // 16,842,752
static const size_t Y_BYTES   = (size_t)3 * NRR * H_ * 2;       // 50,331,648

__device__ __forceinline__ void gload16(const void* g, void* l) {
    __builtin_amdgcn_global_load_lds(
        (const __attribute__((address_space(1))) unsigned int*)g,
        (__attribute__((address_space(3))) unsigned int*)l, 16, 0, 0);
}

// ---------------- weight repack: w[i][o][c][k] -> Wc[m][o][k*H + c] (bf16) ----
__global__ void k_prep_wc(const float* __restrict__ wd, const float* __restrict__ wp,
                          const float* __restrict__ we, bf16* __restrict__ wc) {
    int e = blockIdx.x * 256 + threadIdx.x;
    if (e >= 6 * H_ * KC_) return;
    int m   = e / (H_ * KC_);
    int rem = e % (H_ * KC_);
    int o  = rem / KC_;
    int r2 = rem % KC_;
    int k  = r2 / H_;
    int c  = r2 % H_;
    int p = m >> 1, i = m & 1;
    const float* w = (p == 0) ? wd : (p == 1 ? wp : we);
    float v = w[((size_t)i * H_ * H_ + (size_t)o * H_ + c) * 3 + k];
    wc[e] = (bf16)v;
}

// ---------------- padded bf16 input + zero pad rows of the 3 xp1 buffers -----
__global__ void k_pad(const float* __restrict__ x, bf16* __restrict__ xp0,
                      bf16* __restrict__ xp1) {
    int wid = threadIdx.x >> 6, lane = threadIdx.x & 63;
    int row = blockIdx.x * 4 + wid;               // 0 .. 32*514-1
    int b = row / TP_, tp = row % TP_;
    bf16* d0 = xp0 + (size_t)row * H_ + lane * 8;
    if (tp == 0 || tp == TP_ - 1) {
        bf16x8 z;
#pragma unroll
        for (int i = 0; i < 8; ++i) z[i] = (bf16)0.0f;
        *(bf16x8*)d0 = z;
#pragma unroll
        for (int p = 0; p < 3; ++p)
            *(bf16x8*)(xp1 + p * XPE + (size_t)row * H_ + lane * 8) = z;
    } else {
        const f32x4* p = (const f32x4*)(x + ((size_t)(b * T_ + tp - 1)) * H_ + lane * 8);
        f32x4 u = p[0], v = p[1];
        bf16x8 o;
        o[0] = (bf16)u[0]; o[1] = (bf16)u[1]; o[2] = (bf16)u[2]; o[3] = (bf16)u[3];
        o[4] = (bf16)v[0]; o[5] = (bf16)v[1]; o[6] = (bf16)v[2]; o[7] = (bf16)v[3];
        *(bf16x8*)d0 = o;
    }
}

// ---------------- per-batch inclusive scan of durations ----------------------
__global__ void k_scan(const int* __restrict__ dur, int* __restrict__ csum,
                       float* __restrict__ mel_out) {
    int b = blockIdx.x, t = threadIdx.x;
    __shared__ int s[T_];
    s[t] = dur[b * T_ + t];
    __syncthreads();
    for (int off = 1; off < T_; off <<= 1) {
        int v = (t >= off) ? s[t - off] : 0;
        __syncthreads();
        s[t] += v;
        __syncthreads();
    }
    csum[b * T_ + t] = s[t];
    if (t == T_ - 1) mel_out[b] = (float)((s[t] < L_) ? s[t] : L_);
}

// -------- length regulate + inline bucketize + (x + p_emb + e_emb) gather ----
__global__ void k_gather(const float* __restrict__ x, const float* __restrict__ pemb,
                         const float* __restrict__ eemb, const float* __restrict__ pt,
                         const float* __restrict__ et, const float* __restrict__ pbins,
                         const float* __restrict__ ebins, const int* __restrict__ csum,
                         float* __restrict__ out) {
    int bi = blockIdx.x;
    int b  = bi >> 9;
    int l0 = (bi & 511) << 2;
    __shared__ int cs[T_];
    __shared__ float pb[NB_ - 1], eb[NB_ - 1];
    cs[threadIdx.x]       = csum[b * T_ + threadIdx.x];
    cs[threadIdx.x + 256] = csum[b * T_ + threadIdx.x + 256];
    if (threadIdx.x < NB_ - 1) {
        pb[threadIdx.x] = pbins[threadIdx.x];
        eb[threadIdx.x] = ebins[threadIdx.x];
    }
    __syncthreads();
    int wid = threadIdx.x >> 6, lane = threadIdx.x & 63;
    int l = l0 + wid;
    int mel = cs[T_ - 1]; if (mel > L_) mel = L_;
    float* op = out + ((size_t)(b * L_ + l)) * H_ + lane * 8;
    if (l >= mel) {
        f32x4 z = {0.f, 0.f, 0.f, 0.f};
        ((f32x4*)op)[0] = z;
        ((f32x4*)op)[1] = z;
        return;
    }
    int lo = 0, hi = T_;
    while (lo < hi) { int mid = (lo + hi) >> 1; if (cs[mid] <= l) lo = mid + 1; else hi = mid; }
    int idx = (lo < T_ - 1) ? lo : (T_ - 1);
    int rr = b * T_ + idx;
    float pv = pt[rr], ev = et[rr];
    int pi, ei;
    { int a = 0, c = NB_ - 1; while (a < c) { int mid = (a + c) >> 1; if (pb[mid] < pv) a = mid + 1; else c = mid; } pi = a; }
    { int a = 0, c = NB_ - 1; while (a < c) { int mid = (a + c) >> 1; if (eb[mid] < ev) a = mid + 1; else c = mid; } ei = a; }
    const f32x4* xp = (const f32x4*)(x    + (size_t)rr * H_ + lane * 8);
    const f32x4* pp = (const f32x4*)(pemb + (size_t)pi * H_ + lane * 8);
    const f32x4* ep = (const f32x4*)(eemb + (size_t)ei * H_ + lane * 8);
    ((f32x4*)op)[0] = xp[0] + pp[0] + ep[0];
    ((f32x4*)op)[1] = xp[1] + pp[1] + ep[1];
}

// ============ conv-aware tiled GEMM with tap-reuse (R8-verified optimum) =====
// BM=128, BN=128, H-chunk=64; 4 waves (2Mx2N), per-wave 64x64 out.
// A staged ONCE per H-chunk as a 136-row slab; 3 conv taps read row-shifted
// fragments from the same LDS tile -> 96 MFMA/wave per barrier-pair,
// A-staging cut 3x, 8 K-steps.
// T2 both-sides swizzle: stage key = dest-row&7, read key = (read-row)&7.
// T1: xcd = bid&7; per-XCD: 16 rowblks x all 12 colblks (A slice L2-resident).
template<int LAYER>
__global__ __launch_bounds__(256)
void k_gemm(const bf16* __restrict__ Xp, const bf16* __restrict__ Wall,
            const float* __restrict__ cb0, const float* __restrict__ cb1,
            const float* __restrict__ cb2, bf16* __restrict__ Y) {
    __shared__ bf16 lA[136 * 64];        // 17,408 B
    __shared__ bf16 lB[3 * 128 * 64];    // 49,152 B

    int bid = blockIdx.x;
    int xcd = bid & 7, idx = bid >> 3;   // 1536 blocks: idx 0..191
    int colblk = idx >> 4;               // 0..11  (colblk-major per XCD)
    int rowblk = xcd * 16 + (idx & 15);  // 0..127
    int p  = colblk >> 2;
    int oB = (colblk & 3) * 128;
    int rowBase = rowblk * 128;

    const bf16* A = (LAYER == 0) ? Xp : (Xp + (size_t)p * XPE);
    const bf16* W = Wall + ((size_t)(2 * p + LAYER) * H_ + oB) * KC_;
    const float* cbp  = (p == 0) ? cb0 : (p == 1 ? cb1 : cb2);
    const float* bias = cbp + LAYER * H_;

    int tid = threadIdx.x;
    int wid = tid >> 6, lane = tid & 63;
    int wm = wid >> 1, wn = wid & 1;     // 2M x 2N waves
    int lr = lane & 15, kq = lane >> 4;
    int rsub = lane >> 3;
    int csw  = ((lane & 7) ^ rsub) << 3; // T2 pre-swizzled source col (16B units)
    int b = rowBase >> 9, t0 = rowBase & (T_ - 1);
    const bf16* Abase = A + ((size_t)(b * TP_ + t0)) * H_;

    f32x4 acc[4][4];
#pragma unroll
    for (int m = 0; m < 4; ++m)
#pragma unroll
        for (int n = 0; n < 4; ++n) acc[m][n] = (f32x4){0.f, 0.f, 0.f, 0.f};

    for (int s = 0; s < 8; ++s) {
        int c0 = s * 64;
        // ---- stage A: 17 groups of 8 rows (136 rows) ----
#pragma unroll
        for (int q = 0; q < 5; ++q) {
            int g = q * 4 + wid;
            if (g < 17)
                gload16(Abase + (size_t)(g * 8 + rsub) * H_ + c0 + csw, &lA[g * 8 * 64]);
        }
        // ---- stage B: 3 taps x 16 groups of 8 rows ----
#pragma unroll
        for (int tap = 0; tap < 3; ++tap)
#pragma unroll
            for (int q = 0; q < 4; ++q) {
                int g = q * 4 + wid;
                gload16(W + (size_t)(g * 8 + rsub) * KC_ + tap * H_ + c0 + csw,
                        &lB[(tap * 128 + g * 8) * 64]);
            }
        __syncthreads();   // compiler drains vmcnt before barrier

#pragma unroll
        for (int tap = 0; tap < 3; ++tap) {
            bf16x8 af[4][2], bfr[4][2];
            int ka = (lr + tap) & 7, kb = lr & 7;
#pragma unroll
            for (int m = 0; m < 4; ++m)
#pragma unroll
                for (int kk = 0; kk < 2; ++kk)
                    af[m][kk] = *(const bf16x8*)&lA[(wm * 64 + m * 16 + lr + tap) * 64 +
                                                    ((((kk * 4 + kq) ^ ka)) << 3)];
#pragma unroll
            for (int n = 0; n < 4; ++n)
#pragma unroll
                for (int kk = 0; kk < 2; ++kk)
                    bfr[n][kk] = *(const bf16x8*)&lB[(tap * 128 + wn * 64 + n * 16 + lr) * 64 +
                                                     ((((kk * 4 + kq) ^ kb)) << 3)];
#pragma unroll
            for (int m = 0; m < 4; ++m)
#pragma unroll
                for (int n = 0; n < 4; ++n)
#pragma unroll
                    for (int kk = 0; kk < 2; ++kk)
                        acc[m][n] = __builtin_amdgcn_mfma_f32_16x16x32_bf16(
                            af[m][kk], bfr[n][kk], acc[m][n], 0, 0, 0);
        }
        __syncthreads();
    }

    // D layout: col = lane&15 (o), row = 4*(lane>>4) + reg
#pragma unroll
    for (int n = 0; n < 4; ++n) {
        int o = oB + wn * 64 + n * 16 + lr;
        float bi = bias[o];
#pragma unroll
        for (int m = 0; m < 4; ++m) {
            int row = rowBase + wm * 64 + m * 16 + 4 * kq;
#pragma unroll
            for (int r = 0; r < 4; ++r)
                Y[((size_t)p * NRR + row + r) * H_ + o] = (bf16)fmaxf(acc[m][n][r] + bi, 0.f);
        }
    }
}

// ---------------- batched LayerNorm (layer-0) -> padded xp1[p] ---------------
__global__ void k_ln_store(const bf16* __restrict__ Yin,
                           const float* __restrict__ g0, const float* __restrict__ g1,
                           const float* __restrict__ g2,
                           const float* __restrict__ bb0, const float* __restrict__ bb1,
                           const float* __restrict__ bb2, bf16* __restrict__ xp1) {
    int wid = threadIdx.x >> 6, lane = threadIdx.x & 63;
    int rg = blockIdx.x * 4 + wid;
    int p = rg >> 14, r = rg & (NRR - 1);
    const float* g   = (p == 0) ? g0 : (p == 1 ? g1 : g2);
    const float* bta = (p == 0) ? bb0 : (p == 1 ? bb1 : bb2);
    bf16x8 a = *(const bf16x8*)(Yin + ((size_t)p * NRR + r) * H_ + lane * 8);
    float f[8];
#pragma unroll
    for (int i = 0; i < 8; ++i) f[i] = (float)a[i];
    float s1 = 0.f, s2 = 0.f;
#pragma unroll
    for (int i = 0; i < 8; ++i) { s1 += f[i]; s2 += f[i] * f[i]; }
    for (int m = 1; m < 64; m <<= 1) { s1 += __shfl_xor(s1, m); s2 += __shfl_xor(s2, m); }
    float mean = s1 * (1.f / H_);
    float var  = s2 * (1.f / H_) - mean * mean;
    float rs   = rsqrtf(var + EPS_);
    const f32x4* gp = (const f32x4*)g;
    const f32x4* bp = (const f32x4*)bta;
    f32x4 ga = gp[lane * 2], gb = gp[lane * 2 + 1];
    f32x4 ba = bp[lane * 2], bbv = bp[lane * 2 + 1];
    bf16x8 o;
    o[0] = (bf16)((f[0] - mean) * rs * ga[0] + ba[0]);
    o[1] = (bf16)((f[1] - mean) * rs * ga[1] + ba[1]);
    o[2] = (bf16)((f[2] - mean) * rs * ga[2] + ba[2]);
    o[3] = (bf16)((f[3] - mean) * rs * ga[3] + ba[3]);
    o[4] = (bf16)((f[4] - mean) * rs * gb[0] + bbv[0]);
    o[5] = (bf16)((f[5] - mean) * rs * gb[1] + bbv[1]);
    o[6] = (bf16)((f[6] - mean) * rs * gb[2] + bbv[2]);
    o[7] = (bf16)((f[7] - mean) * rs * gb[3] + bbv[3]);
    int bb = r >> 9, t = r & (T_ - 1);
    *(bf16x8*)(xp1 + (size_t)p * XPE + ((size_t)(bb * TP_ + t + 1)) * H_ + lane * 8) = o;
}

// ---------------- batched LayerNorm (layer-1) + linear H->1 + mask -----------
__global__ void k_ln_linear(const bf16* __restrict__ Yin,
                            const float* __restrict__ g0, const float* __restrict__ g1,
                            const float* __restrict__ g2,
                            const float* __restrict__ bb0, const float* __restrict__ bb1,
                            const float* __restrict__ bb2,
                            const float* __restrict__ w0p, const float* __restrict__ w1p,
                            const float* __restrict__ w2p,
                            const float* __restrict__ lb0, const float* __restrict__ lb1,
                            const float* __restrict__ lb2,
                            const unsigned char* __restrict__ mask,
                            float* __restrict__ o0, float* __restrict__ o1,
                            float* __restrict__ o2) {
    int wid = threadIdx.x >> 6, lane = threadIdx.x & 63;
    int rg = blockIdx.x * 4 + wid;
    int p = rg >> 14, r = rg & (NRR - 1);
    const float* g   = ((p == 0) ? g0 : (p == 1 ? g1 : g2)) + H_;
    const float* bta = ((p == 0) ? bb0 : (p == 1 ? bb1 : bb2)) + H_;
    const float* lw  = (p == 0) ? w0p : (p == 1 ? w1p : w2p);
    const float* lb  = (p == 0) ? lb0 : (p == 1 ? lb1 : lb2);
    float*       op  = (p == 0) ? o0 : (p == 1 ? o1 : o2);
    bf16x8 a = *(const bf16x8*)(Yin + ((size_t)p * NRR + r) * H_ + lane * 8);
    float f[8];
#pragma unroll
    for (int i = 0; i < 8; ++i) f[i] = (float)a[i];
    float s1 = 0.f, s2 = 0.f;
#pragma unroll
    for (int i = 0; i < 8; ++i) { s1 += f[i]; s2 += f[i] * f[i]; }
    for (int m = 1; m < 64; m <<= 1) { s1 += __shfl_xor(s1, m); s2 += __shfl_xor(s2, m); }
    float mean = s1 * (1.f / H_);
    float var  = s2 * (1.f / H_) - mean * mean;
    float rs   = rsqrtf(var + EPS_);
    const f32x4* gp = (const f32x4*)g;
    const f32x4* bp = (const f32x4*)bta;
    const f32x4* wp = (const f32x4*)lw;
    f32x4 ga = gp[lane * 2], gb = gp[lane * 2 + 1];
    f32x4 ba = bp[lane * 2], bbv = bp[lane * 2 + 1];
    f32x4 wa = wp[lane * 2], wb = wp[lane * 2 + 1];
    float s = ((f[0] - mean) * rs * ga[0] + ba[0]) * wa[0]
            + ((f[1] - mean) * rs * ga[1] + ba[1]) * wa[1]
            + ((f[2] - mean) * rs * ga[2] + ba[2]) * wa[2]
            + ((f[3] - mean) * rs * ga[3] + ba[3]) * wa[3]
            + ((f[4] - mean) * rs * gb[0] + bbv[0]) * wb[0]
            + ((f[5] - mean) * rs * gb[1] + bbv[1]) * wb[1]
            + ((f[6] - mean) * rs * gb[2] + bbv[2]) * wb[2]
            + ((f[7] - mean) * rs * gb[3] + bbv[3]) * wb[3];
    for (int m = 1; m < 64; m <<= 1) s += __shfl_xor(s, m);
    if (lane == 0) op[r] = mask[r] ? 0.f : (s + lb[0]);
}

extern "C" void kernel_launch(void* const* d_in, const int* in_sizes, int n_in,
                              void* d_out, int out_size, void* d_ws, size_t ws_size,
                              hipStream_t stream) {
    const float* x  = (const float*)d_in[0];
    const unsigned char* mask = (const unsigned char*)d_in[1];
    const int*   dur = (const int*)d_in[2];
    const float* pt  = (const float*)d_in[3];
    const float* et  = (const float*)d_in[4];
    const float* cw[3]    = {(const float*)d_in[6],  (const float*)d_in[12], (const float*)d_in[18]};
    const float* cb[3]    = {(const float*)d_in[7],  (const float*)d_in[13], (const float*)d_in[19]};
    const float* lg[3]    = {(const float*)d_in[8],  (const float*)d_in[14], (const float*)d_in[20]};
    const float* lbn[3]   = {(const float*)d_in[9],  (const float*)d_in[15], (const float*)d_in[21]};
    const float* lw[3]    = {(const float*)d_in[10], (const float*)d_in[16], (const float*)d_in[22]};
    const float* lbias[3] = {(const float*)d_in[11], (const float*)d_in[17], (const float*)d_in[23]};
    const float* pbins = (const float*)d_in[24];
    const float* ebins = (const float*)d_in[25];
    const float* pemb  = (const float*)d_in[26];
    const float* eemb  = (const float*)d_in[27];

    float* out0 = (float*)d_out;
    const size_t OUT0 = (size_t)B_ * L_ * H_;
    float* pitch_out  = out0 + OUT0;
    float* energy_out = pitch_out + NRR;
    float* logd_out   = energy_out + NRR;
    float* mel_out    = logd_out + NRR;

    char* ws = (char*)d_ws;
    bf16*  wc   = (bf16*)ws;
    bf16*  xp0  = (bf16*)(ws + WC_BYTES);
    bf16*  xp1  = (bf16*)(ws + WC_BYTES + XP_BYTES);          // 3 buffers
    bf16*  y    = (bf16*)(ws + WC_BYTES + 4 * XP_BYTES);      // [3][NRR][512]
    int*   csum = (int*)(ws + WC_BYTES + 4 * XP_BYTES + Y_BYTES);

    k_prep_wc<<<(6 * H_ * KC_ + 255) / 256, 256, 0, stream>>>(cw[0], cw[1], cw[2], wc);
    k_pad<<<B_ * TP_ / 4, 256, 0, stream>>>(x, xp0, xp1);
    k_scan<<<B_, T_, 0, stream>>>(dur, csum, mel_out);
    k_gather<<<B_ * L_ / 4, 256, 0, stream>>>(x, pemb, eemb, pt, et, pbins, ebins, csum, out0);

    k_gemm<0><<<1536, 256, 0, stream>>>(xp0, wc, cb[0], cb[1], cb[2], y);
    k_ln_store<<<3 * NRR / 4, 256, 0, stream>>>(y, lg[0], lg[1], lg[2],
                                                lbn[0], lbn[1], lbn[2], xp1);
    k_gemm<1><<<1536, 256, 0, stream>>>(xp1, wc, cb[0], cb[1], cb[2], y);
    k_ln_linear<<<3 * NRR / 4, 256, 0, stream>>>(y, lg[0], lg[1], lg[2],
                                                 lbn[0], lbn[1], lbn[2],
                                                 lw[0], lw[1], lw[2],
                                                 lbias[0], lbias[1], lbias[2],
                                                 mask, logd_out, pitch_out, energy_out);
}